// Round 9
// baseline (181.525 us; speedup 1.0000x reference)
//
#include <hip/hip_runtime.h>
#include <hip/hip_bf16.h>

// GCN_85804856639970 — 2-layer GCN + FC head, MI355X.
// N=50000, E=800000, 128->128->64, head 64x64. fp32 in/out, edge_index int32.
//
// R21 = R20 (172.3 us, best) + atomic-free single-pass binning + ci-pipelined aggs.
//  (1) binning: deterministic per-(chunk,bucket) staging segments (SCAP=160,
//      mean 68, overflow P~3e-20; scheme field-proven in R19 whose regression
//      was the gemm-LDS change, not this) -> no gcnt global atomics, ONE LDS
//      pass (position atomics only), bincnt fully rewritten each launch (no
//      memset). k_wt loses gcnt zeroing.
//  (2) aggs: software-pipeline the slab-pointer loads — prefetch next round's
//      cp uint4s (index wrapped &63: stays inside the 64-entry sentinel slab)
//      so the ~200cy ci latency overlaps the current round's gathers.
// Kept from R20: quad-split aggs (16 lanes/node, uint4 gathers), two-phase
// single-writer CSR, gemm1||binning fusion, dinv prescale of hs1r/hs2,
// sentinel-padded slabs, agg+GEMM epilogue fusion, k_wt global W1T (R19
// lesson: LDS-transposing W1 in k_front loses to coalesced L2-hot W1T reads).
// Requires N <= 65535 (16-bit ids incl. sentinel N), NBIN <= 64.

typedef __attribute__((ext_vector_type(8))) short bf16x8;
typedef __attribute__((ext_vector_type(4))) float f32x4;

#define SLAB 64    // per-node adjacency capacity (max observed deg ~45)
#define SCAP 160   // staging capacity per (chunk,bucket) cell (mean 68, +11 sigma)
#define NBIN 60    // edge chunks; grid D1 = 196 gemm mega-blocks + 60 bin = 256

__device__ __forceinline__ unsigned short f2bf(float f) {
    unsigned u = __float_as_uint(f);
    unsigned r = (u + 0x7FFFu + ((u >> 16) & 1u)) >> 16;
    return (unsigned short)r;
}
__device__ __forceinline__ float bf16_lo(unsigned u) {
    return __uint_as_float((u & 0xFFFFu) << 16);
}
__device__ __forceinline__ float bf16_hi(unsigned u) {
    return __uint_as_float(u & 0xFFFF0000u);
}

#define UNPK16(cA, cB, ci)                                        \
    ci[0] = cA.x & 0xFFFFu;  ci[1] = cA.x >> 16;                  \
    ci[2] = cA.y & 0xFFFFu;  ci[3] = cA.y >> 16;                  \
    ci[4] = cA.z & 0xFFFFu;  ci[5] = cA.z >> 16;                  \
    ci[6] = cA.w & 0xFFFFu;  ci[7] = cA.w >> 16;                  \
    ci[8] = cB.x & 0xFFFFu;  ci[9] = cB.x >> 16;                  \
    ci[10] = cB.y & 0xFFFFu; ci[11] = cB.y >> 16;                 \
    ci[12] = cB.z & 0xFFFFu; ci[13] = cB.z >> 16;                 \
    ci[14] = cB.w & 0xFFFFu; ci[15] = cB.w >> 16;

// ---------------- weight transpose + misc init (tiny pre-dispatch) ----------------

__global__ void k_wt(const float* __restrict__ W1, const float* __restrict__ W2,
                     const float* __restrict__ fcW,
                     unsigned short* __restrict__ W1T, unsigned short* __restrict__ W2T,
                     unsigned short* __restrict__ fcWT,
                     unsigned short* __restrict__ hs1r, unsigned short* __restrict__ hs2,
                     int n) {
    int j = blockIdx.x * blockDim.x + threadIdx.x;
    if (j < 16384) {
        int m = j >> 7, k = j & 127;
        W1T[j] = f2bf(W1[k * 128 + m]);
    } else if (j < 24576) {
        int q = j - 16384;
        int m = q >> 7, k = q & 127;
        W2T[q] = f2bf(W2[k * 64 + m]);
    } else if (j < 28672) {
        int q = j - 24576;
        int m = q >> 6, k = q & 63;
        fcWT[q] = f2bf(fcW[k * 64 + m]);
    } else if (j < 28800) {         // zero row N of hs1r (sentinel target)
        hs1r[(size_t)n * 128 + (j - 28672)] = 0;
    } else if (j < 28864) {         // zero row N of hs2
        hs2[(size_t)n * 64 + (j - 28800)] = 0;
    }
}

// ---------------- gemm1 tile body: 64 rows of bf16(X[128] @ W1[128x128]) ----------------

__device__ __forceinline__ void gemm1_body(const float* __restrict__ X,
                                           const unsigned short* __restrict__ W1T,
                                           unsigned short* __restrict__ outp,
                                           int n, int blk, int tid,
                                           unsigned short* xs) {
    constexpr int LDW = 136;
    int base = blk * 64;
    for (int idx = tid; idx < 64 * 32; idx += 256) {
        int r = idx >> 5, c = idx & 31;
        int row = base + r;
        float4 v = make_float4(0.f, 0.f, 0.f, 0.f);
        if (row < n) v = ((const float4*)X)[(size_t)row * 32 + c];
        unsigned short* dp = &xs[r * LDW + c * 4];
        dp[0] = f2bf(v.x); dp[1] = f2bf(v.y); dp[2] = f2bf(v.z); dp[3] = f2bf(v.w);
    }
    __syncthreads();

    int wave = tid >> 6, lane = tid & 63;
    int quad = lane >> 4, l16 = lane & 15;
    int rbase = wave * 16;

    bf16x8 af[4];
#pragma unroll
    for (int kb = 0; kb < 4; ++kb)
        af[kb] = *(const bf16x8*)&xs[(rbase + l16) * LDW + kb * 32 + quad * 8];

#pragma unroll
    for (int jt = 0; jt < 8; ++jt) {
        f32x4 acc = {0.f, 0.f, 0.f, 0.f};
#pragma unroll
        for (int kb = 0; kb < 4; ++kb) {
            bf16x8 bf = *(const bf16x8*)&W1T[(size_t)(jt * 16 + l16) * 128 + kb * 32 + quad * 8];
            acc = __builtin_amdgcn_mfma_f32_16x16x32_bf16(af[kb], bf, acc, 0, 0, 0);
        }
#pragma unroll
        for (int r = 0; r < 4; ++r) {
            int row = base + rbase + quad * 4 + r;
            if (row < n)
                outp[(size_t)row * 128 + jt * 16 + l16] = f2bf(acc[r]);
        }
    }
}

// ---------------- D1: gemm1 mega-blocks (4 tiles each) + atomic-free binning ----------------

__global__ __launch_bounds__(1024) void k_front(
    const int* __restrict__ src, const int* __restrict__ dst, int e,
    unsigned* __restrict__ staging, int* __restrict__ bincnt,
    const float* __restrict__ x, const unsigned short* __restrict__ W1T,
    unsigned short* __restrict__ hs1r, int n, int nbk, int ngemm, int binch) {
    __shared__ __align__(16) unsigned short xs4[4][64 * 136];
    __shared__ int bpos[256];
    int bid = (int)blockIdx.x, tid = (int)threadIdx.x;

    if (bid < ngemm) {
        int tile = tid >> 8;
        gemm1_body(x, W1T, hs1r, n, bid * 4 + tile, tid & 255, xs4[tile]);
    } else {
        int c = bid - ngemm;
        if (tid < 256) bpos[tid] = 0;
        __syncthreads();
        int e0 = c * binch;
        int lim = e - e0; if (lim > binch) lim = binch; if (lim < 0) lim = 0;
        for (int i = tid; i < lim; i += 1024) {
            int d = dst[e0 + i], s = src[e0 + i];
            int b = d >> 8;
            int p = atomicAdd(&bpos[b], 1);
            if (p < SCAP)
                staging[((size_t)c * nbk + b) * SCAP + p] =
                    ((unsigned)d << 16) | (unsigned)s;
        }
        __syncthreads();
        if (tid < nbk) {
            int v = bpos[tid];
            bincnt[c * nbk + tid] = v < SCAP ? v : SCAP;  // every cell rewritten: no memset
        }
    }
}

// ---------------- D2: bucket-exclusive scatter + cnt/dinv + in-place hs1 prescale ----------------

__global__ __launch_bounds__(1024) void k_scatter(
    const unsigned* __restrict__ staging, const int* __restrict__ bincnt,
    int* __restrict__ cnt, unsigned short* __restrict__ col,
    float* __restrict__ dinv, unsigned* __restrict__ hs1u, int n, int nbk, int nbin) {
    __shared__ int lcnt[256];
    __shared__ __align__(16) unsigned short ls[256 * SLAB];  // 32 KB
    __shared__ float sdi[256];
    __shared__ int scnt[64];                                  // NBIN <= 64
    int b = (int)blockIdx.x, t = (int)threadIdx.x;
    if (t < 256) lcnt[t] = 0;
    if (t < nbin) scnt[t] = bincnt[t * nbk + b];
    unsigned sent2 = (unsigned)n | ((unsigned)n << 16);
    for (int i = t; i < 256 * SLAB / 2; i += 1024) ((unsigned*)ls)[i] = sent2;
    __syncthreads();
    int g = t >> 6, l = t & 63;  // 16 wave-groups walk the 60 segments
    for (int c = g; c < nbin; c += 16) {
        int ccnt = scnt[c];
        const unsigned* seg = staging + ((size_t)c * nbk + b) * SCAP;
        for (int i = l; i < ccnt; i += 64) {
            unsigned pk = seg[i];
            int dl = (int)(pk >> 16) & 255;
            int pos = atomicAdd(&lcnt[dl], 1);
            if (pos < SLAB) ls[(dl << 6) + pos] = (unsigned short)(pk & 0xFFFFu);
        }
    }
    __syncthreads();
    int base = b << 8;
    const uint4* lsv = (const uint4*)ls;
    uint4* gv = (uint4*)(col + ((size_t)base << 6));
    for (int i = t; i < 256 * SLAB / 8; i += 1024) gv[i] = lsv[i];
    if (t < 256) {
        int c = lcnt[t];
        float dv = rsqrtf((float)c + 1.0f);
        sdi[t] = dv;
        cnt[base + t] = c;            // cnt/dinv sized Npad: pad rows get c=0
        dinv[base + t] = dv;
    }
    __syncthreads();
    // in-place pre-scale of this bucket's hs1 rows (single-writer): row *= dinv
    int rows = n - base; if (rows > 256) rows = 256; if (rows < 0) rows = 0;
    unsigned* hp = hs1u + ((size_t)base << 6);  // 64 uints (128 bf16) per row
    for (int i = t; i < rows * 64; i += 1024) {
        int r = i >> 6;
        unsigned u = hp[i];
        float sc = sdi[r];
        unsigned lo = f2bf(sc * bf16_lo(u));
        unsigned hi = f2bf(sc * bf16_hi(u));
        hp[i] = lo | (hi << 16);
    }
}

// ---------------- D3: layer-1 agg (quad-split, ci-pipelined) + fused @W2 -> hs2 ----------------

__global__ __launch_bounds__(256) void k_aggg128(
    const int* __restrict__ cnt, const unsigned short* __restrict__ col,
    const unsigned short* __restrict__ hs, const float* __restrict__ dinv,
    const float* __restrict__ bias, const unsigned short* __restrict__ W2T,
    unsigned short* __restrict__ hs2, int n) {
    __shared__ __align__(16) unsigned short ys[16 * 136];
    __shared__ float ldi[16];
    int tid = (int)threadIdx.x;
    int w = tid >> 6, lane = tid & 63;
    int q = lane >> 4, l16 = lane & 15;
    int gbase = (int)blockIdx.x * 16;
    const uint4* hp4 = (const uint4*)hs;  // row = 16 x uint4 (256 B)

    int node = gbase + w * 4 + q;
    int c = cnt[node]; if (c > SLAB) c = SLAB;
    int dm = c;
    int o = __shfl_xor(dm, 16); if (o > dm) dm = o;
    o = __shfl_xor(dm, 32); if (o > dm) dm = o;   // max over the wave's 4 nodes

    const unsigned short* cp = &col[(size_t)node * SLAB];
    float di = dinv[node];
    int h0 = node < n ? node : n;
    uint4 su = hp4[(size_t)h0 * 16 + l16];  // prescaled: di*row
    float a0 = bf16_lo(su.x), a1 = bf16_hi(su.x);
    float a2 = bf16_lo(su.y), a3 = bf16_hi(su.y);
    float a4 = bf16_lo(su.z), a5 = bf16_hi(su.z);
    float a6 = bf16_lo(su.w), a7 = bf16_hi(su.w);

    // ci software pipeline: prefetch next round's slab pointers (&63 wrap
    // keeps reads inside the 64-entry sentinel slab)
    uint4 cA = *(const uint4*)&cp[0];
    uint4 cB = *(const uint4*)&cp[8];
    for (int i = 0; i < dm; i += 16) {
        int nx = (i + 16) & 63;
        uint4 nA = *(const uint4*)&cp[nx];
        uint4 nB = *(const uint4*)&cp[nx + 8];
        unsigned ci[16];
        UNPK16(cA, cB, ci)
        uint4 u[16];
#pragma unroll
        for (int j = 0; j < 16; ++j) u[j] = hp4[(size_t)ci[j] * 16 + l16];
#pragma unroll
        for (int j = 0; j < 16; ++j) {
            a0 += bf16_lo(u[j].x); a1 += bf16_hi(u[j].x);
            a2 += bf16_lo(u[j].y); a3 += bf16_hi(u[j].y);
            a4 += bf16_lo(u[j].z); a5 += bf16_hi(u[j].z);
            a6 += bf16_lo(u[j].w); a7 += bf16_hi(u[j].w);
        }
        cA = nA; cB = nB;
    }

    float4 bv0 = *(const float4*)&bias[l16 * 8];
    float4 bv1 = *(const float4*)&bias[l16 * 8 + 4];
    float v0 = fmaxf(di * a0 + bv0.x, 0.0f);
    float v1 = fmaxf(di * a1 + bv0.y, 0.0f);
    float v2 = fmaxf(di * a2 + bv0.z, 0.0f);
    float v3 = fmaxf(di * a3 + bv0.w, 0.0f);
    float v4 = fmaxf(di * a4 + bv1.x, 0.0f);
    float v5 = fmaxf(di * a5 + bv1.y, 0.0f);
    float v6 = fmaxf(di * a6 + bv1.z, 0.0f);
    float v7 = fmaxf(di * a7 + bv1.w, 0.0f);
    uint4 ov;
    ov.x = (unsigned)f2bf(v0) | ((unsigned)f2bf(v1) << 16);
    ov.y = (unsigned)f2bf(v2) | ((unsigned)f2bf(v3) << 16);
    ov.z = (unsigned)f2bf(v4) | ((unsigned)f2bf(v5) << 16);
    ov.w = (unsigned)f2bf(v6) | ((unsigned)f2bf(v7) << 16);
    *(uint4*)((char*)ys + (size_t)(w * 4 + q) * 272 + l16 * 16) = ov;
    if (l16 == 0) ldi[w * 4 + q] = di;
    __syncthreads();

    // fused GEMM: ys(16x128) @ W2T -> hs2(16x64), scaled by dinv[row] (prescale for layer-2 agg)
    int quad = lane >> 4, l16b = lane & 15;
    bf16x8 a[4];
#pragma unroll
    for (int kb = 0; kb < 4; ++kb)
        a[kb] = *(const bf16x8*)&ys[l16b * 136 + kb * 32 + quad * 8];
    f32x4 acc = {0.f, 0.f, 0.f, 0.f};
#pragma unroll
    for (int kb = 0; kb < 4; ++kb) {
        bf16x8 bf = *(const bf16x8*)&W2T[(size_t)(w * 16 + l16b) * 128 + kb * 32 + quad * 8];
        acc = __builtin_amdgcn_mfma_f32_16x16x32_bf16(a[kb], bf, acc, 0, 0, 0);
    }
#pragma unroll
    for (int r = 0; r < 4; ++r) {
        int lrow = quad * 4 + r;
        int row = gbase + lrow;
        if (row < n)
            hs2[(size_t)row * 64 + w * 16 + l16b] = f2bf(acc[r] * ldi[lrow]);
    }
}

// ---------------- D4: layer-2 agg (quad-split, ci-pipelined) + fused FC head ----------------

__global__ __launch_bounds__(256) void k_aggg64(
    const int* __restrict__ cnt, const unsigned short* __restrict__ col,
    const unsigned short* __restrict__ hs, const float* __restrict__ dinv,
    const float* __restrict__ bias, const unsigned short* __restrict__ fcWT,
    const float* __restrict__ fcb, float* __restrict__ out, int n) {
    __shared__ __align__(16) unsigned short yt[16 * 72];
    int tid = (int)threadIdx.x;
    int w = tid >> 6, lane = tid & 63;
    int q = lane >> 4, l16 = lane & 15;
    int gbase = (int)blockIdx.x * 16;
    const uint2* hp2 = (const uint2*)hs;  // row = 16 x uint2 (128 B)

    int node = gbase + w * 4 + q;
    int c = cnt[node]; if (c > SLAB) c = SLAB;
    int dm = c;
    int o = __shfl_xor(dm, 16); if (o > dm) dm = o;
    o = __shfl_xor(dm, 32); if (o > dm) dm = o;

    const unsigned short* cp = &col[(size_t)node * SLAB];
    float di = dinv[node];
    int h0 = node < n ? node : n;
    uint2 su = hp2[(size_t)h0 * 16 + l16];  // rows pre-scaled by src dinv
    float a0 = bf16_lo(su.x), a1 = bf16_hi(su.x);
    float a2 = bf16_lo(su.y), a3 = bf16_hi(su.y);

    uint4 cA = *(const uint4*)&cp[0];
    uint4 cB = *(const uint4*)&cp[8];
    for (int i = 0; i < dm; i += 16) {
        int nx = (i + 16) & 63;
        uint4 nA = *(const uint4*)&cp[nx];
        uint4 nB = *(const uint4*)&cp[nx + 8];
        unsigned ci[16];
        UNPK16(cA, cB, ci)
        uint2 u[16];
#pragma unroll
        for (int j = 0; j < 16; ++j) u[j] = hp2[(size_t)ci[j] * 16 + l16];
#pragma unroll
        for (int j = 0; j < 16; ++j) {
            a0 += bf16_lo(u[j].x); a1 += bf16_hi(u[j].x);
            a2 += bf16_lo(u[j].y); a3 += bf16_hi(u[j].y);
        }
        cA = nA; cB = nB;
    }

    float4 bv = *(const float4*)&bias[l16 * 4];
    float v0 = fmaxf(di * a0 + bv.x, 0.0f);
    float v1 = fmaxf(di * a1 + bv.y, 0.0f);
    float v2 = fmaxf(di * a2 + bv.z, 0.0f);
    float v3 = fmaxf(di * a3 + bv.w, 0.0f);
    uint2 ov;
    ov.x = (unsigned)f2bf(v0) | ((unsigned)f2bf(v1) << 16);
    ov.y = (unsigned)f2bf(v2) | ((unsigned)f2bf(v3) << 16);
    *(uint2*)((char*)yt + (size_t)(w * 4 + q) * 144 + l16 * 8) = ov;
    __syncthreads();

    // fused head: yt(16x64) @ fcWT -> out(16x64) fp32 + fcb
    int quad = lane >> 4, l16b = lane & 15;
    bf16x8 a[2];
#pragma unroll
    for (int kb = 0; kb < 2; ++kb)
        a[kb] = *(const bf16x8*)&yt[l16b * 72 + kb * 32 + quad * 8];
    f32x4 acc = {0.f, 0.f, 0.f, 0.f};
#pragma unroll
    for (int kb = 0; kb < 2; ++kb) {
        bf16x8 bf = *(const bf16x8*)&fcWT[(size_t)(w * 16 + l16b) * 64 + kb * 32 + quad * 8];
        acc = __builtin_amdgcn_mfma_f32_16x16x32_bf16(a[kb], bf, acc, 0, 0, 0);
    }
    float bv2 = fcb[w * 16 + l16b];
#pragma unroll
    for (int r = 0; r < 4; ++r) {
        int row = gbase + quad * 4 + r;
        if (row < n)
            out[(size_t)row * 64 + w * 16 + l16b] = acc[r] + bv2;
    }
}

// ---------------- launch ----------------

extern "C" void kernel_launch(void* const* d_in, const int* in_sizes, int n_in,
                              void* d_out, int out_size, void* d_ws, size_t ws_size,
                              hipStream_t stream) {
    const float* x   = (const float*)d_in[0];
    const int*   ei  = (const int*)d_in[1];
    const float* W1  = (const float*)d_in[2];
    const float* b1  = (const float*)d_in[3];
    const float* W2  = (const float*)d_in[4];
    const float* b2  = (const float*)d_in[5];
    const float* fcW = (const float*)d_in[6];
    const float* fcb = (const float*)d_in[7];
    float* out = (float*)d_out;

    const int N = in_sizes[0] / 128;
    const int E = in_sizes[1] / 2;
    const int* src = ei;
    const int* dst = ei + E;

    const int NB    = (N + 255) >> 8;           // 196 buckets of 256 nodes
    const int Npad  = NB << 8;                  // rows incl. bucket padding
    const int nbin  = NBIN;                     // 60 chunks
    const int binch = (E + nbin - 1) / nbin;    // 13334 edges/chunk
    const int gg64  = (N + 63) / 64;            // 782 gemm1 tiles
    const int ngemm = (gg64 + 3) / 4;           // 196 mega-blocks
    const int nagg  = (N + 15) / 16;            // 3125

    // ---- workspace carve (16B-aligned), peak ~34 MB ----
    auto align16 = [](size_t v) { return (v + 15) & ~(size_t)15; };
    char* p = (char*)d_ws;
    unsigned* staging = (unsigned*)p;          p += align16(sizeof(unsigned) * (size_t)nbin * NB * SCAP);
    int* bincnt = (int*)p;                     p += align16(sizeof(int) * (size_t)nbin * NB);
    int* cnt = (int*)p;                        p += align16(sizeof(int) * Npad);
    float* dinv = (float*)p;                   p += align16(sizeof(float) * Npad);
    unsigned short* col = (unsigned short*)p;  p += align16(sizeof(unsigned short) * (size_t)Npad * SLAB);
    unsigned short* W1T = (unsigned short*)p;  p += align16(2 * 128 * 128);
    unsigned short* W2T = (unsigned short*)p;  p += align16(2 * 64 * 128);
    unsigned short* fcWT = (unsigned short*)p; p += align16(2 * 64 * 64);
    unsigned short* hs1r = (unsigned short*)p; p += align16(2 * ((size_t)N + 1) * 128);
    unsigned short* hs2 = (unsigned short*)p;  p += align16(2 * ((size_t)N + 1) * 64);

    // init: weight transposes + sentinel rows
    k_wt<<<114, 256, 0, stream>>>(W1, W2, fcW, W1T, W2T, fcWT, hs1r, hs2, N);

    // D1: gemm1 (196 mega-blocks) + atomic-free binning (60 chunks)
    k_front<<<ngemm + nbin, 1024, 0, stream>>>(src, dst, E, staging, bincnt,
                                               x, W1T, hs1r, N, NB, ngemm, binch);

    // D2: bucket-exclusive scatter -> sentinel-padded col + cnt + dinv + prescale
    k_scatter<<<NB, 1024, 0, stream>>>(staging, bincnt, cnt, col, dinv,
                                       (unsigned*)hs1r, N, NB, nbin);

    // D3: layer-1 agg (quad-split, ci-pipelined) fused with @W2 -> hs2 (prescaled)
    k_aggg128<<<nagg, 256, 0, stream>>>(cnt, col, hs1r, dinv, b1, W2T, hs2, N);

    // D4: layer-2 agg (quad-split, ci-pipelined) fused with FC head -> out (fp32)
    k_aggg64<<<nagg, 256, 0, stream>>>(cnt, col, hs2, dinv, b2, fcWT, fcb, out, N);
}

// Round 10
// 171.933 us; speedup vs baseline: 1.0558x; 1.0558x over previous
//
#include <hip/hip_runtime.h>
#include <hip/hip_bf16.h>

// GCN_85804856639970 — 2-layer GCN + FC head, MI355X.
// N=50000, E=800000, 128->128->64, head 64x64. fp32 in/out, edge_index int32.
//
// R22 = R20 (172.3 us, best) + ci-pipelined aggs + per-quad loop bounds.
// R21 post-mortem (+9.2): bundled binning restructure (prime suspect: scatter
// went contiguous->60 tiny segments; staging 4.8->7.5MB) with ci-pipelining;
// reverted the binning/scatter side to R20 verbatim, kept ci-pipelining.
// New isolated change: aggs run each quad's gather loop to its OWN degree
// (was wave-max of 4 nodes): finished quads are exec-masked and stop issuing
// gathers (~30% less wasted gather issue at Poisson(16) degrees), and the two
// shfl_xor max-reductions disappear. Masked lanes add nothing -> numerics
// identical.
// Kept from R20: quad-split aggs (16 lanes/node, uint4 gathers), two-phase
// single-writer CSR (two-pass binning, BCAP staging, gcnt atomics), gemm1 ||
// binning fusion, dinv prescale of hs1r/hs2, sentinel-padded slabs, agg+GEMM
// epilogue fusion, k_wt global W1T (R19: LDS-transposed W1 loses).
// Requires N <= 65535 (16-bit ids incl. sentinel N).

typedef __attribute__((ext_vector_type(8))) short bf16x8;
typedef __attribute__((ext_vector_type(4))) float f32x4;

#define SLAB 64    // per-node adjacency capacity (max observed deg ~45)
#define BCAP 6144  // staging capacity per 256-node bucket (mean 4096, +32 sigma)
#define BINCH 8192 // edges per phase-1 binning block

__device__ __forceinline__ unsigned short f2bf(float f) {
    unsigned u = __float_as_uint(f);
    unsigned r = (u + 0x7FFFu + ((u >> 16) & 1u)) >> 16;
    return (unsigned short)r;
}
__device__ __forceinline__ float bf16_lo(unsigned u) {
    return __uint_as_float((u & 0xFFFFu) << 16);
}
__device__ __forceinline__ float bf16_hi(unsigned u) {
    return __uint_as_float(u & 0xFFFF0000u);
}

#define UNPK16(cA, cB, ci)                                        \
    ci[0] = cA.x & 0xFFFFu;  ci[1] = cA.x >> 16;                  \
    ci[2] = cA.y & 0xFFFFu;  ci[3] = cA.y >> 16;                  \
    ci[4] = cA.z & 0xFFFFu;  ci[5] = cA.z >> 16;                  \
    ci[6] = cA.w & 0xFFFFu;  ci[7] = cA.w >> 16;                  \
    ci[8] = cB.x & 0xFFFFu;  ci[9] = cB.x >> 16;                  \
    ci[10] = cB.y & 0xFFFFu; ci[11] = cB.y >> 16;                 \
    ci[12] = cB.z & 0xFFFFu; ci[13] = cB.z >> 16;                 \
    ci[14] = cB.w & 0xFFFFu; ci[15] = cB.w >> 16;

// ---------------- weight transpose + misc init (tiny pre-dispatch) ----------------

__global__ void k_wt(const float* __restrict__ W1, const float* __restrict__ W2,
                     const float* __restrict__ fcW,
                     unsigned short* __restrict__ W1T, unsigned short* __restrict__ W2T,
                     unsigned short* __restrict__ fcWT, int* __restrict__ gcnt,
                     unsigned short* __restrict__ hs1r, unsigned short* __restrict__ hs2,
                     int n) {
    int j = blockIdx.x * blockDim.x + threadIdx.x;
    if (j < 256) gcnt[j] = 0;  // NB <= 256
    if (j < 16384) {
        int m = j >> 7, k = j & 127;
        W1T[j] = f2bf(W1[k * 128 + m]);
    } else if (j < 24576) {
        int q = j - 16384;
        int m = q >> 7, k = q & 127;
        W2T[q] = f2bf(W2[k * 64 + m]);
    } else if (j < 28672) {
        int q = j - 24576;
        int m = q >> 6, k = q & 63;
        fcWT[q] = f2bf(fcW[k * 64 + m]);
    } else if (j < 28800) {         // zero row N of hs1r (sentinel target)
        hs1r[(size_t)n * 128 + (j - 28672)] = 0;
    } else if (j < 28864) {         // zero row N of hs2
        hs2[(size_t)n * 64 + (j - 28800)] = 0;
    }
}

// ---------------- gemm1 tile body: 64 rows of bf16(X[128] @ W1[128x128]) ----------------

__device__ __forceinline__ void gemm1_body(const float* __restrict__ X,
                                           const unsigned short* __restrict__ W1T,
                                           unsigned short* __restrict__ outp,
                                           int n, int blk, int tid,
                                           unsigned short* xs) {
    constexpr int LDW = 136;
    int base = blk * 64;
    for (int idx = tid; idx < 64 * 32; idx += 256) {
        int r = idx >> 5, c = idx & 31;
        int row = base + r;
        float4 v = make_float4(0.f, 0.f, 0.f, 0.f);
        if (row < n) v = ((const float4*)X)[(size_t)row * 32 + c];
        unsigned short* dp = &xs[r * LDW + c * 4];
        dp[0] = f2bf(v.x); dp[1] = f2bf(v.y); dp[2] = f2bf(v.z); dp[3] = f2bf(v.w);
    }
    __syncthreads();

    int wave = tid >> 6, lane = tid & 63;
    int quad = lane >> 4, l16 = lane & 15;
    int rbase = wave * 16;

    bf16x8 af[4];
#pragma unroll
    for (int kb = 0; kb < 4; ++kb)
        af[kb] = *(const bf16x8*)&xs[(rbase + l16) * LDW + kb * 32 + quad * 8];

#pragma unroll
    for (int jt = 0; jt < 8; ++jt) {
        f32x4 acc = {0.f, 0.f, 0.f, 0.f};
#pragma unroll
        for (int kb = 0; kb < 4; ++kb) {
            bf16x8 bf = *(const bf16x8*)&W1T[(size_t)(jt * 16 + l16) * 128 + kb * 32 + quad * 8];
            acc = __builtin_amdgcn_mfma_f32_16x16x32_bf16(af[kb], bf, acc, 0, 0, 0);
        }
#pragma unroll
        for (int r = 0; r < 4; ++r) {
            int row = base + rbase + quad * 4 + r;
            if (row < n)
                outp[(size_t)row * 128 + jt * 16 + l16] = f2bf(acc[r]);
        }
    }
}

// ---------------- D1: gemm1 mega-blocks (4 tiles each) + edge binning ----------------

__global__ __launch_bounds__(1024) void k_front(
    const int* __restrict__ src, const int* __restrict__ dst, int e,
    int* __restrict__ gcnt, unsigned* __restrict__ staging,
    const float* __restrict__ x, const unsigned short* __restrict__ W1T,
    unsigned short* __restrict__ hs1r, int n, int nbk, int ngemm) {
    __shared__ __align__(16) unsigned short xs4[4][64 * 136];
    __shared__ int bcnt[256], bpos[256], gofs[256];
    int bid = (int)blockIdx.x, tid = (int)threadIdx.x;

    if (bid < ngemm) {
        int tile = tid >> 8;
        gemm1_body(x, W1T, hs1r, n, bid * 4 + tile, tid & 255, xs4[tile]);
    } else {
        int b0 = bid - ngemm;
        if (tid < 256) { bcnt[tid] = 0; bpos[tid] = 0; }
        __syncthreads();
        int e0 = b0 * BINCH;
        int d[8], s[8];
#pragma unroll
        for (int r = 0; r < 8; ++r) {
            int i = e0 + r * 1024 + tid;
            if (i < e) { d[r] = dst[i]; s[r] = src[i]; } else d[r] = -1;
        }
#pragma unroll
        for (int r = 0; r < 8; ++r)
            if (d[r] >= 0) atomicAdd(&bcnt[d[r] >> 8], 1);
        __syncthreads();
        if (tid < nbk) {
            int c = bcnt[tid];
            gofs[tid] = c ? atomicAdd(&gcnt[tid], c) : 0;
        }
        __syncthreads();
#pragma unroll
        for (int r = 0; r < 8; ++r) {
            if (d[r] >= 0) {
                int b = d[r] >> 8;
                int p = atomicAdd(&bpos[b], 1);
                int idx = gofs[b] + p;
                if (idx < BCAP)
                    staging[(size_t)b * BCAP + idx] =
                        ((unsigned)d[r] << 16) | (unsigned)s[r];
            }
        }
    }
}

// ---------------- D2: bucket-exclusive scatter + in-place hs1 dinv pre-scale ----------------

__global__ __launch_bounds__(1024) void k_scatter(
    const unsigned* __restrict__ staging, const int* __restrict__ gcnt,
    int* __restrict__ cnt, unsigned short* __restrict__ col,
    float* __restrict__ dinv, unsigned* __restrict__ hs1u, int n) {
    __shared__ int lcnt[256];
    __shared__ __align__(16) unsigned short ls[256 * SLAB];  // 32 KB
    __shared__ float sdi[256];
    int b = (int)blockIdx.x, t = (int)threadIdx.x;
    if (t < 256) lcnt[t] = 0;
    unsigned sent2 = (unsigned)n | ((unsigned)n << 16);
    for (int i = t; i < 256 * SLAB / 2; i += 1024) ((unsigned*)ls)[i] = sent2;
    __syncthreads();
    int eb = gcnt[b]; if (eb > BCAP) eb = BCAP;
    const unsigned* sp = staging + (size_t)b * BCAP;
    for (int i = t; i < eb; i += 1024) {
        unsigned pk = sp[i];
        int dl = (int)(pk >> 16) & 255;
        int pos = atomicAdd(&lcnt[dl], 1);
        if (pos < SLAB) ls[(dl << 6) + pos] = (unsigned short)(pk & 0xFFFFu);
    }
    __syncthreads();
    int base = b << 8;
    const uint4* lsv = (const uint4*)ls;
    uint4* gv = (uint4*)(col + ((size_t)base << 6));
    for (int i = t; i < 256 * SLAB / 8; i += 1024) gv[i] = lsv[i];
    if (t < 256) {
        int c = lcnt[t];
        float dv = rsqrtf((float)c + 1.0f);
        sdi[t] = dv;
        cnt[base + t] = c;            // cnt/dinv sized Npad: pad rows get c=0
        dinv[base + t] = dv;
    }
    __syncthreads();
    // in-place pre-scale of this bucket's hs1 rows (single-writer): row *= dinv
    int rows = n - base; if (rows > 256) rows = 256; if (rows < 0) rows = 0;
    unsigned* hp = hs1u + ((size_t)base << 6);  // 64 uints (128 bf16) per row
    for (int i = t; i < rows * 64; i += 1024) {
        int r = i >> 6;
        unsigned u = hp[i];
        float sc = sdi[r];
        unsigned lo = f2bf(sc * bf16_lo(u));
        unsigned hi = f2bf(sc * bf16_hi(u));
        hp[i] = lo | (hi << 16);
    }
}

// ---------------- D3: layer-1 agg (quad-split, per-quad bound, ci-pipelined) + fused @W2 ----------------
// Wave serves 4 nodes; quad q owns node gbase+w*4+q, runs to its OWN degree
// (finished quads exec-mask off and stop issuing gathers). ci pointers for the
// next round prefetched (&63 wrap stays inside the sentinel slab).

__global__ __launch_bounds__(256) void k_aggg128(
    const int* __restrict__ cnt, const unsigned short* __restrict__ col,
    const unsigned short* __restrict__ hs, const float* __restrict__ dinv,
    const float* __restrict__ bias, const unsigned short* __restrict__ W2T,
    unsigned short* __restrict__ hs2, int n) {
    __shared__ __align__(16) unsigned short ys[16 * 136];
    __shared__ float ldi[16];
    int tid = (int)threadIdx.x;
    int w = tid >> 6, lane = tid & 63;
    int q = lane >> 4, l16 = lane & 15;
    int gbase = (int)blockIdx.x * 16;
    const uint4* hp4 = (const uint4*)hs;  // row = 16 x uint4 (256 B)

    int node = gbase + w * 4 + q;
    int c = cnt[node]; if (c > SLAB) c = SLAB;

    const unsigned short* cp = &col[(size_t)node * SLAB];
    float di = dinv[node];
    int h0 = node < n ? node : n;
    uint4 su = hp4[(size_t)h0 * 16 + l16];  // prescaled: di*row
    float a0 = bf16_lo(su.x), a1 = bf16_hi(su.x);
    float a2 = bf16_lo(su.y), a3 = bf16_hi(su.y);
    float a4 = bf16_lo(su.z), a5 = bf16_hi(su.z);
    float a6 = bf16_lo(su.w), a7 = bf16_hi(su.w);

    uint4 cA = *(const uint4*)&cp[0];
    uint4 cB = *(const uint4*)&cp[8];
    for (int i = 0; i < c; i += 16) {
        int nx = (i + 16) & 63;
        uint4 nA = *(const uint4*)&cp[nx];
        uint4 nB = *(const uint4*)&cp[nx + 8];
        unsigned ci[16];
        UNPK16(cA, cB, ci)
        uint4 u[16];
#pragma unroll
        for (int j = 0; j < 16; ++j) u[j] = hp4[(size_t)ci[j] * 16 + l16];
#pragma unroll
        for (int j = 0; j < 16; ++j) {
            a0 += bf16_lo(u[j].x); a1 += bf16_hi(u[j].x);
            a2 += bf16_lo(u[j].y); a3 += bf16_hi(u[j].y);
            a4 += bf16_lo(u[j].z); a5 += bf16_hi(u[j].z);
            a6 += bf16_lo(u[j].w); a7 += bf16_hi(u[j].w);
        }
        cA = nA; cB = nB;
    }

    float4 bv0 = *(const float4*)&bias[l16 * 8];
    float4 bv1 = *(const float4*)&bias[l16 * 8 + 4];
    float v0 = fmaxf(di * a0 + bv0.x, 0.0f);
    float v1 = fmaxf(di * a1 + bv0.y, 0.0f);
    float v2 = fmaxf(di * a2 + bv0.z, 0.0f);
    float v3 = fmaxf(di * a3 + bv0.w, 0.0f);
    float v4 = fmaxf(di * a4 + bv1.x, 0.0f);
    float v5 = fmaxf(di * a5 + bv1.y, 0.0f);
    float v6 = fmaxf(di * a6 + bv1.z, 0.0f);
    float v7 = fmaxf(di * a7 + bv1.w, 0.0f);
    uint4 ov;
    ov.x = (unsigned)f2bf(v0) | ((unsigned)f2bf(v1) << 16);
    ov.y = (unsigned)f2bf(v2) | ((unsigned)f2bf(v3) << 16);
    ov.z = (unsigned)f2bf(v4) | ((unsigned)f2bf(v5) << 16);
    ov.w = (unsigned)f2bf(v6) | ((unsigned)f2bf(v7) << 16);
    *(uint4*)((char*)ys + (size_t)(w * 4 + q) * 272 + l16 * 16) = ov;
    if (l16 == 0) ldi[w * 4 + q] = di;
    __syncthreads();

    // fused GEMM: ys(16x128) @ W2T -> hs2(16x64), scaled by dinv[row] (prescale for layer-2 agg)
    int quad = lane >> 4, l16b = lane & 15;
    bf16x8 a[4];
#pragma unroll
    for (int kb = 0; kb < 4; ++kb)
        a[kb] = *(const bf16x8*)&ys[l16b * 136 + kb * 32 + quad * 8];
    f32x4 acc = {0.f, 0.f, 0.f, 0.f};
#pragma unroll
    for (int kb = 0; kb < 4; ++kb) {
        bf16x8 bf = *(const bf16x8*)&W2T[(size_t)(w * 16 + l16b) * 128 + kb * 32 + quad * 8];
        acc = __builtin_amdgcn_mfma_f32_16x16x32_bf16(a[kb], bf, acc, 0, 0, 0);
    }
#pragma unroll
    for (int r = 0; r < 4; ++r) {
        int lrow = quad * 4 + r;
        int row = gbase + lrow;
        if (row < n)
            hs2[(size_t)row * 64 + w * 16 + l16b] = f2bf(acc[r] * ldi[lrow]);
    }
}

// ---------------- D4: layer-2 agg (quad-split, per-quad bound, ci-pipelined) + fused FC head ----------------

__global__ __launch_bounds__(256) void k_aggg64(
    const int* __restrict__ cnt, const unsigned short* __restrict__ col,
    const unsigned short* __restrict__ hs, const float* __restrict__ dinv,
    const float* __restrict__ bias, const unsigned short* __restrict__ fcWT,
    const float* __restrict__ fcb, float* __restrict__ out, int n) {
    __shared__ __align__(16) unsigned short yt[16 * 72];
    int tid = (int)threadIdx.x;
    int w = tid >> 6, lane = tid & 63;
    int q = lane >> 4, l16 = lane & 15;
    int gbase = (int)blockIdx.x * 16;
    const uint2* hp2 = (const uint2*)hs;  // row = 16 x uint2 (128 B)

    int node = gbase + w * 4 + q;
    int c = cnt[node]; if (c > SLAB) c = SLAB;

    const unsigned short* cp = &col[(size_t)node * SLAB];
    float di = dinv[node];
    int h0 = node < n ? node : n;
    uint2 su = hp2[(size_t)h0 * 16 + l16];  // rows pre-scaled by src dinv
    float a0 = bf16_lo(su.x), a1 = bf16_hi(su.x);
    float a2 = bf16_lo(su.y), a3 = bf16_hi(su.y);

    uint4 cA = *(const uint4*)&cp[0];
    uint4 cB = *(const uint4*)&cp[8];
    for (int i = 0; i < c; i += 16) {
        int nx = (i + 16) & 63;
        uint4 nA = *(const uint4*)&cp[nx];
        uint4 nB = *(const uint4*)&cp[nx + 8];
        unsigned ci[16];
        UNPK16(cA, cB, ci)
        uint2 u[16];
#pragma unroll
        for (int j = 0; j < 16; ++j) u[j] = hp2[(size_t)ci[j] * 16 + l16];
#pragma unroll
        for (int j = 0; j < 16; ++j) {
            a0 += bf16_lo(u[j].x); a1 += bf16_hi(u[j].x);
            a2 += bf16_lo(u[j].y); a3 += bf16_hi(u[j].y);
        }
        cA = nA; cB = nB;
    }

    float4 bv = *(const float4*)&bias[l16 * 4];
    float v0 = fmaxf(di * a0 + bv.x, 0.0f);
    float v1 = fmaxf(di * a1 + bv.y, 0.0f);
    float v2 = fmaxf(di * a2 + bv.z, 0.0f);
    float v3 = fmaxf(di * a3 + bv.w, 0.0f);
    uint2 ov;
    ov.x = (unsigned)f2bf(v0) | ((unsigned)f2bf(v1) << 16);
    ov.y = (unsigned)f2bf(v2) | ((unsigned)f2bf(v3) << 16);
    *(uint2*)((char*)yt + (size_t)(w * 4 + q) * 144 + l16 * 8) = ov;
    __syncthreads();

    // fused head: yt(16x64) @ fcWT -> out(16x64) fp32 + fcb
    int quad = lane >> 4, l16b = lane & 15;
    bf16x8 a[2];
#pragma unroll
    for (int kb = 0; kb < 2; ++kb)
        a[kb] = *(const bf16x8*)&yt[l16b * 72 + kb * 32 + quad * 8];
    f32x4 acc = {0.f, 0.f, 0.f, 0.f};
#pragma unroll
    for (int kb = 0; kb < 2; ++kb) {
        bf16x8 bf = *(const bf16x8*)&fcWT[(size_t)(w * 16 + l16b) * 64 + kb * 32 + quad * 8];
        acc = __builtin_amdgcn_mfma_f32_16x16x32_bf16(a[kb], bf, acc, 0, 0, 0);
    }
    float bv2 = fcb[w * 16 + l16b];
#pragma unroll
    for (int r = 0; r < 4; ++r) {
        int row = gbase + quad * 4 + r;
        if (row < n)
            out[(size_t)row * 64 + w * 16 + l16b] = acc[r] + bv2;
    }
}

// ---------------- launch ----------------

extern "C" void kernel_launch(void* const* d_in, const int* in_sizes, int n_in,
                              void* d_out, int out_size, void* d_ws, size_t ws_size,
                              hipStream_t stream) {
    const float* x   = (const float*)d_in[0];
    const int*   ei  = (const int*)d_in[1];
    const float* W1  = (const float*)d_in[2];
    const float* b1  = (const float*)d_in[3];
    const float* W2  = (const float*)d_in[4];
    const float* b2  = (const float*)d_in[5];
    const float* fcW = (const float*)d_in[6];
    const float* fcb = (const float*)d_in[7];
    float* out = (float*)d_out;

    const int N = in_sizes[0] / 128;
    const int E = in_sizes[1] / 2;
    const int* src = ei;
    const int* dst = ei + E;

    const int NB    = (N + 255) >> 8;          // 196 buckets of 256 nodes
    const int Npad  = NB << 8;                 // rows incl. bucket padding
    const int nbin  = (E + BINCH - 1) / BINCH; // 98
    const int gg64  = (N + 63) / 64;           // 782 gemm1 tiles
    const int ngemm = (gg64 + 3) / 4;          // 196 mega-blocks
    const int nagg  = (N + 15) / 16;           // 3125

    // ---- workspace carve (16B-aligned), peak ~31 MB ----
    auto align16 = [](size_t v) { return (v + 15) & ~(size_t)15; };
    char* p = (char*)d_ws;
    int* gcnt = (int*)p;                       p += align16(sizeof(int) * 256);
    unsigned* staging = (unsigned*)p;          p += align16(sizeof(unsigned) * (size_t)NB * BCAP);
    int* cnt = (int*)p;                        p += align16(sizeof(int) * Npad);
    float* dinv = (float*)p;                   p += align16(sizeof(float) * Npad);
    unsigned short* col = (unsigned short*)p;  p += align16(sizeof(unsigned short) * (size_t)Npad * SLAB);
    unsigned short* W1T = (unsigned short*)p;  p += align16(2 * 128 * 128);
    unsigned short* W2T = (unsigned short*)p;  p += align16(2 * 64 * 128);
    unsigned short* fcWT = (unsigned short*)p; p += align16(2 * 64 * 64);
    unsigned short* hs1r = (unsigned short*)p; p += align16(2 * ((size_t)N + 1) * 128);
    unsigned short* hs2 = (unsigned short*)p;  p += align16(2 * ((size_t)N + 1) * 64);

    // init: weights transpose, gcnt zero, sentinel rows
    k_wt<<<114, 256, 0, stream>>>(W1, W2, fcW, W1T, W2T, fcWT, gcnt,
                                  hs1r, hs2, N);

    // D1: gemm1 (196 mega-blocks, dispatched first) + binning (98)
    k_front<<<ngemm + nbin, 1024, 0, stream>>>(src, dst, E, gcnt, staging,
                                               x, W1T, hs1r, N, NB, ngemm);
    // D2: bucket-exclusive scatter -> sentinel-padded col + cnt + dinv,
    //     then in-place dinv pre-scale of this bucket's hs1 rows
    k_scatter<<<NB, 1024, 0, stream>>>(staging, gcnt, cnt, col, dinv,
                                       (unsigned*)hs1r, N);

    // D3: layer-1 agg (quad-split, per-quad bound, ci-pipelined) + fused @W2 -> hs2
    k_aggg128<<<nagg, 256, 0, stream>>>(cnt, col, hs1r, dinv, b1, W2T, hs2, N);

    // D4: layer-2 agg (quad-split, per-quad bound, ci-pipelined) + fused FC head -> out
    k_aggg64<<<nagg, 256, 0, stream>>>(cnt, col, hs2, dinv, b2, fcWT, fcb, out, N);
}